// Round 22
// baseline (465.747 us; speedup 1.0000x reference)
//
#include <hip/hip_runtime.h>
#include <hip/hip_bf16.h>

typedef unsigned short ushort_t;
typedef unsigned int uint_t;

#define NN    10000
#define NE    320000
#define NL    4
#define EBLK  64        // edges per block (4 threads per edge)
#define NEBLK 5000      // NE / EBLK exactly
#define NPB   64        // nodes per block in pre_kernel (4 threads per node)
#define NNODEBLK 157    // ceil(NN / NPB)
#define NPB2  16        // nodes per block in node_kernel (16 threads per node)
#define NODEBLK2 625    // NN / NPB2 exactly, no tail

// ---- workspace float offsets -------------------------------------------------
#define OFF_FIELD 0        // 30000
#define OFF_HH    30000    // 640000
#define OFF_CSUM  670000   // 30000  (contiguous with MAGG for one memset)
#define OFF_MAGG  700000   // 640000 -> float end 1340000
// ---- int region (starts at float offset 1340000) ----------------------------
#define IOFF_CNTI   0        // 10000
#define IOFF_OFF    10000    // 10001
#define IOFF_CURSOR 20001    // 10000
#define IOFF_PERM   30001    // 320000
#define IOFF_PRER   350004   // 320000 uints (f16-pair preR; 16B-aligned)
#define IOFF_PREC   670004   // 320000 uints
#define IOFF_WCONV  990004   // 65536 uints (4 layers x 16384) -> int end 1055540
// total ws = (1340000 + 1055540) * 4 = 9,582,160 B
// per-layer wconv block of 16384 uints:
#define WC_EW1  0      // 4096  eW1 rows 0..127, pair-major kp*64+j
#define WC_EW2  4096   // 2048  eW2, swizzled channel-major (edge sWp phys layout)
#define WC_CW1  6144   // 2048  cW1, same swizzled layout
#define WC_VW1  8192   // 2048  vW1 pair-major
#define WC_GW1  10240  // 2048  gW1 pair-major
#define WC_NW1  12288  // 4096  nW1 pair-major

// fast silu: v_rcp_f32 instead of IEEE divide (~1e-7 rel err, VALU-bound paths)
__device__ __forceinline__ float silu(float x) {
    return x * __builtin_amdgcn_rcpf(1.0f + __expf(-x));
}

// ---- f16 pair helpers (clang builtins use __fp16 V2h / V8h) ------------------
typedef __fp16 half2v __attribute__((ext_vector_type(2)));
typedef __fp16 f16x8 __attribute__((ext_vector_type(8)));
typedef float f32x4 __attribute__((ext_vector_type(4)));
union U4H8 { uint4 u; f16x8 h; };
__device__ __forceinline__ half2v u2h(uint_t u) {
    union { uint_t u; half2v h; } x; x.u = u; return x.h;
}
__device__ __forceinline__ uint_t h2u(half2v h) {
    union { half2v h; uint_t u; } x; x.h = h; return x.u;
}
__device__ __forceinline__ half2v pkrtz(float a, float b) {
    return __builtin_amdgcn_cvt_pkrtz(a, b);
}
__device__ __forceinline__ float dot2h(half2v a, uint_t w, float c) {
#if __has_builtin(__builtin_amdgcn_fdot2)
    return __builtin_amdgcn_fdot2(a, u2h(w), c, false);
#else
    union { uint_t u; __fp16 h[2]; } x; x.u = w;
    return c + (float)a.x * (float)x.h[0] + (float)a.y * (float)x.h[1];
#endif
}
__device__ __forceinline__ ushort_t f2hbits(float f) {
    union { __fp16 h; ushort_t u; } x; x.h = (__fp16)f; return x.u;
}

// ---- weight pre-conversion: fp32 -> f16-pair formats, once per call ----------
// Layer l handled by block l. All consumer layouts preserved exactly.
__global__ __launch_bounds__(256) void wconv_kernel(
    const float* __restrict__ eW1, const float* __restrict__ eW2,
    const float* __restrict__ cW1, const float* __restrict__ vW1,
    const float* __restrict__ gW1, const float* __restrict__ nW1,
    uint_t* __restrict__ out)
{
    const int l = blockIdx.x;
    const int t = threadIdx.x;
    uint_t* o = out + l * 16384;
    const float* e1 = eW1 + l * 8384;
    const float* e2 = eW2 + l * 4096;
    const float* c1 = cW1 + l * 4096;
    const float* v1 = vW1 + l * 4096;
    const float* g1 = gW1 + l * 4096;
    const float* n1 = nW1 + l * 8192;

    for (int i = t; i < 4096; i += 256)        // eW1 rows 0..127, pair-major
        o[WC_EW1 + i] = h2u(pkrtz(e1[(i >> 6) * 128 + (i & 63)],
                                  e1[(i >> 6) * 128 + 64 + (i & 63)]));
    for (int i = t; i < 2048; i += 256) {      // eW2 swizzled channel-major
        const int kp = i >> 6, bc = i & 63;
        const uint_t v = h2u(pkrtz(e2[kp * 128 + bc], e2[kp * 128 + 64 + bc]));
        o[WC_EW2 + bc * 32 + (((kp >> 2) ^ (bc & 7)) << 2) + (kp & 3)] = v;
    }
    for (int i = t; i < 2048; i += 256) {      // cW1 swizzled channel-major
        const int kp = i >> 6, bc = i & 63;
        const uint_t v = h2u(pkrtz(c1[kp * 128 + bc], c1[kp * 128 + 64 + bc]));
        o[WC_CW1 + bc * 32 + (((kp >> 2) ^ (bc & 7)) << 2) + (kp & 3)] = v;
    }
    for (int i = t; i < 2048; i += 256)        // vW1 pair-major
        o[WC_VW1 + i] = h2u(pkrtz(v1[(i >> 6) * 128 + (i & 63)],
                                  v1[(i >> 6) * 128 + 64 + (i & 63)]));
    for (int i = t; i < 2048; i += 256)        // gW1 pair-major
        o[WC_GW1 + i] = h2u(pkrtz(g1[(i >> 6) * 128 + (i & 63)],
                                  g1[(i >> 6) * 128 + 64 + (i & 63)]));
    for (int i = t; i < 4096; i += 256)        // nW1 pair-major
        o[WC_NW1 + i] = h2u(pkrtz(n1[(i >> 6) * 128 + (i & 63)],
                                  n1[(i >> 6) * 128 + 64 + (i & 63)]));
}

// ---- CSR build: per-row int counts ------------------------------------------
__global__ __launch_bounds__(256) void counti_kernel(const int* __restrict__ rows,
                                                     int* __restrict__ cnti) {
    const int e = blockIdx.x * 256 + threadIdx.x;
    if (e < NE) {
        int r = rows[e];
        r = ((uint_t)r < (uint_t)NN) ? r : 0;
        atomicAdd(&cnti[r], 1);
    }
}

// ---- CSR build: exclusive scan over 10000 counts (single block) --------------
__global__ __launch_bounds__(1024) void scan_kernel(const int* __restrict__ cnti,
                                                    int* __restrict__ off,
                                                    int* __restrict__ cursor) {
    __shared__ int part[1024];
    const int t = threadIdx.x;
    const int base = t * 10;
    int loc[10];
    int s = 0;
    #pragma unroll
    for (int i = 0; i < 10; i++) {
        const int idx = base + i;
        const int v = (idx < NN) ? cnti[idx] : 0;
        loc[i] = s; s += v;
    }
    part[t] = s;
    __syncthreads();
    const int own = s;
    for (int d = 1; d < 1024; d <<= 1) {
        const int v = (t >= d) ? part[t - d] : 0;
        __syncthreads();
        part[t] += v;
        __syncthreads();
    }
    const int excl = part[t] - own;
    #pragma unroll
    for (int i = 0; i < 10; i++) {
        const int idx = base + i;
        if (idx < NN) { const int o = excl + loc[i]; off[idx] = o; cursor[idx] = o; }
    }
    if (t == 0) off[NN] = NE;
}

// ---- CSR build: scatter edge ids into row-sorted order -----------------------
__global__ __launch_bounds__(256) void scatter_kernel(const int* __restrict__ rows,
                                                      int* __restrict__ cursor,
                                                      int* __restrict__ perm) {
    const int e = blockIdx.x * 256 + threadIdx.x;
    if (e < NE) {
        int r = rows[e];
        r = ((uint_t)r < (uint_t)NN) ? r : 0;
        const int pos = atomicAdd(&cursor[r], 1);
        if ((uint_t)pos < (uint_t)NE) perm[pos] = e;
    }
}

// ---- field network + node embedding + coord init (once per call) ------------
__global__ __launch_bounds__(256) void node_init(
    const float* __restrict__ hsrc, const float* __restrict__ xsrc,
    const float* __restrict__ vsrc, const int* __restrict__ charges,
    const float* __restrict__ cls,
    const float* __restrict__ fW1, const float* __restrict__ fb1,
    const float* __restrict__ fW2, const float* __restrict__ fb2,
    const float* __restrict__ fW3, const float* __restrict__ fb3,
    const float* __restrict__ embW, const float* __restrict__ embb,
    float* __restrict__ coord, float* __restrict__ field, float* __restrict__ hh)
{
    __shared__ float sFW1[704], sFW2[1024], sFW3[96];
    __shared__ float sFB1[32], sFB2[32], sFB3[3], sCLS[32], sEW[64], sEB[64];
    const int t = threadIdx.x;
    for (int i = t; i < 704; i += 256) sFW1[i] = fW1[i];
    for (int i = t; i < 1024; i += 256) sFW2[i] = fW2[i];
    if (t < 96) sFW3[t] = fW3[t];
    if (t < 32) { sFB1[t] = fb1[t]; sFB2[t] = fb2[t]; sCLS[t] = cls[t]; }
    if (t < 3)  sFB3[t] = fb3[t];
    if (t < 64) { sEW[t] = embW[t]; sEB[t] = embb[t]; }
    __syncthreads();

    const int n = blockIdx.x * 256 + t;
    if (n >= NN) return;

    float fin[22];
    #pragma unroll
    for (int d = 0; d < 3; d++) {
        fin[d]     = xsrc[3 * n + d];
        fin[3 + d] = vsrc[3 * n + d];
        coord[3 * n + d] = fin[d];
    }
    int ci = charges[n];
    ci = ((uint_t)ci < 2u) ? ci : 0;
    const int cix = ci * 16;
    #pragma unroll
    for (int k = 0; k < 16; k++) fin[6 + k] = sCLS[cix + k];

    float h1[32];
    #pragma unroll
    for (int j = 0; j < 32; j++) h1[j] = sFB1[j];
    #pragma unroll
    for (int k = 0; k < 22; k++) {
        const float v = fin[k];
        #pragma unroll
        for (int j = 0; j < 32; j++) h1[j] += v * sFW1[k * 32 + j];
    }
    #pragma unroll
    for (int j = 0; j < 32; j++) h1[j] = silu(h1[j]);

    float h2[32];
    #pragma unroll
    for (int j = 0; j < 32; j++) h2[j] = sFB2[j];
    #pragma unroll
    for (int k = 0; k < 32; k++) {
        const float v = h1[k];
        #pragma unroll
        for (int j = 0; j < 32; j++) h2[j] += v * sFW2[k * 32 + j];
    }
    #pragma unroll
    for (int j = 0; j < 32; j++) h2[j] = silu(h2[j]);

    #pragma unroll
    for (int d = 0; d < 3; d++) {
        float s = sFB3[d];
        #pragma unroll
        for (int j = 0; j < 32; j++) s += h2[j] * sFW3[j * 3 + d];
        field[3 * n + d] = s;
    }

    const float hv = hsrc[n];
    #pragma unroll
    for (int j = 0; j < 64; j++) hh[(size_t)n * 64 + j] = hv * sEW[j] + sEB[j];
}

// ---- layer-0 pre kernel (staging now a uint4 copy from wconv) ----------------
__global__ __launch_bounds__(256, 4) void pre_kernel(
    const float* __restrict__ hh,
    const uint_t* __restrict__ w1p, const float* __restrict__ gEB1,
    uint_t* __restrict__ preR, uint_t* __restrict__ preC)
{
    __shared__ __align__(16) uint_t sW1p[4096];   // rows 0..127 f16-paired, 16 KB
    __shared__ float sB1[64];
    const int t = threadIdx.x;
    for (int i = t; i < 1024; i += 256)
        ((uint4*)sW1p)[i] = ((const uint4*)w1p)[i];
    if (t < 64) sB1[t] = gEB1[t];
    __syncthreads();

    const int ni = t >> 2, q = t & 3;
    int n = blockIdx.x * NPB + ni;
    const bool valid = (n < NN);
    n = valid ? n : (NN - 1);
    const float4* h4p = (const float4*)(hh + (size_t)n * 64);

    float acc[16];
    #pragma unroll
    for (int j = 0; j < 16; j++) acc[j] = sB1[q * 16 + j];
    #pragma unroll
    for (int kk = 0; kk < 16; kk++) {
        const float4 a = h4p[kk];
        const half2v p0 = pkrtz(a.x, a.y);
        const half2v p1 = pkrtz(a.z, a.w);
        const uint4* w0 = (const uint4*)&sW1p[(2 * kk) * 64 + q * 16];
        const uint4* w1 = (const uint4*)&sW1p[(2 * kk + 1) * 64 + q * 16];
        #pragma unroll
        for (int j4 = 0; j4 < 4; j4++) {
            const uint4 wa = w0[j4], wb = w1[j4];
            acc[4*j4+0] = dot2h(p1, wb.x, dot2h(p0, wa.x, acc[4*j4+0]));
            acc[4*j4+1] = dot2h(p1, wb.y, dot2h(p0, wa.y, acc[4*j4+1]));
            acc[4*j4+2] = dot2h(p1, wb.z, dot2h(p0, wa.z, acc[4*j4+2]));
            acc[4*j4+3] = dot2h(p1, wb.w, dot2h(p0, wa.w, acc[4*j4+3]));
        }
    }
    if (valid) {
        uint4 o0, o1;
        o0.x = h2u(pkrtz(acc[0],  acc[1]));  o0.y = h2u(pkrtz(acc[2],  acc[3]));
        o0.z = h2u(pkrtz(acc[4],  acc[5]));  o0.w = h2u(pkrtz(acc[6],  acc[7]));
        o1.x = h2u(pkrtz(acc[8],  acc[9]));  o1.y = h2u(pkrtz(acc[10], acc[11]));
        o1.z = h2u(pkrtz(acc[12], acc[13])); o1.w = h2u(pkrtz(acc[14], acc[15]));
        uint4* dst = (uint4*)(preR + (size_t)n * 32 + q * 8);
        dst[0] = o0; dst[1] = o1;
    }

    #pragma unroll
    for (int j = 0; j < 16; j++) acc[j] = 0.f;
    #pragma unroll
    for (int kk = 0; kk < 16; kk++) {
        const float4 a = h4p[kk];
        const half2v p0 = pkrtz(a.x, a.y);
        const half2v p1 = pkrtz(a.z, a.w);
        const uint4* w0 = (const uint4*)&sW1p[(32 + 2 * kk) * 64 + q * 16];
        const uint4* w1 = (const uint4*)&sW1p[(33 + 2 * kk) * 64 + q * 16];
        #pragma unroll
        for (int j4 = 0; j4 < 4; j4++) {
            const uint4 wa = w0[j4], wb = w1[j4];
            acc[4*j4+0] = dot2h(p1, wb.x, dot2h(p0, wa.x, acc[4*j4+0]));
            acc[4*j4+1] = dot2h(p1, wb.y, dot2h(p0, wa.y, acc[4*j4+1]));
            acc[4*j4+2] = dot2h(p1, wb.z, dot2h(p0, wa.z, acc[4*j4+2]));
            acc[4*j4+3] = dot2h(p1, wb.w, dot2h(p0, wa.w, acc[4*j4+3]));
        }
    }
    if (valid) {
        uint4 o0, o1;
        o0.x = h2u(pkrtz(acc[0],  acc[1]));  o0.y = h2u(pkrtz(acc[2],  acc[3]));
        o0.z = h2u(pkrtz(acc[4],  acc[5]));  o0.w = h2u(pkrtz(acc[6],  acc[7]));
        o1.x = h2u(pkrtz(acc[8],  acc[9]));  o1.y = h2u(pkrtz(acc[10], acc[11]));
        o1.z = h2u(pkrtz(acc[12], acc[13])); o1.w = h2u(pkrtz(acc[14], acc[15]));
        uint4* dst = (uint4*)(preC + (size_t)n * 32 + q * 8);
        dst[0] = o0; dst[1] = o1;
    }
}

// ---- per-layer edge kernel: MFMA GEMMs, wconv-staged weights -----------------
// Round-22 vs r21: W2/cW1 staging are pure uint4 copies of the pre-swizzled
// wconv buffers (no cvt_pkrtz, no scatter); cwr write-late is 2 linear uint4
// stores. All read-side layouts and GEMMs byte-identical to r21 (verified).
__global__ __launch_bounds__(256, 8) void edge_kernel(
    const int* __restrict__ rows, const int* __restrict__ cols,
    const int* __restrict__ perm,
    const float* __restrict__ coord,
    const float* __restrict__ eattr,
    const float* __restrict__ gEW1,                 // only ext rows 128..130
    const uint_t* __restrict__ ewp,                 // wconv layer block
    const float* __restrict__ gEB2,
    const float* __restrict__ gCB1, const float* __restrict__ gCW2,
    const uint_t* __restrict__ preR, const uint_t* __restrict__ preC,
    float* __restrict__ csum, float* __restrict__ magg)
{
    __shared__ __align__(16) uint_t tileh[EBLK * 32];  // f16-pair activations, 8 KB
    __shared__ __align__(16) uint_t sWp[2048];         // W2 then cW1 (aliased), 8 KB
    __shared__ float sExtW[3 * 64];                    // W1 rows 128..130 fp32
    __shared__ float sB2[64], sCB1[64], sCW2v[64];
    __shared__ float scw[EBLK];                        // per-edge cw
    __shared__ int   sr[EBLK], sc[EBLK], se[EBLK];
    __shared__ int   segstart[EBLK + 1];
    __shared__ int   snseg;

    const int t = threadIdx.x;
    // T1 bijective XCD chunk swizzle (5000 % 8 == 0)
    const int bid = blockIdx.x;
    const int lb  = (bid & 7) * (NEBLK / 8) + (bid >> 3);

    // ---- T14 issue-early: cW1 (pre-swizzled) global->reg ----
    const uint4 cwr0 = ((const uint4*)(ewp + WC_CW1))[t];
    const uint4 cwr1 = ((const uint4*)(ewp + WC_CW1))[t + 256];

    // ---- stage W2 (pre-swizzled uint4 copy), ext rows, biases ----
    for (int i = t; i < 512; i += 256)
        ((uint4*)sWp)[i] = ((const uint4*)(ewp + WC_EW2))[i];
    if (t < 192) sExtW[t] = gEW1[8192 + t];        // rows 128..130
    if (t < 64) { sB2[t] = gEB2[t]; sCB1[t] = gCB1[t]; sCW2v[t] = gCW2[t]; }

    if (t < EBLK) {
        int e = perm[lb * EBLK + t];
        e = ((uint_t)e < (uint_t)NE) ? e : 0;
        int r = rows[e], c = cols[e];
        r = ((uint_t)r < (uint_t)NN) ? r : 0;
        c = ((uint_t)c < (uint_t)NN) ? c : 0;
        se[t] = e; sr[t] = r; sc[t] = c;
    }
    __syncthreads();

    if (t < EBLK) {
        const int flag = (t == 0) ? 1 : ((sr[t] != sr[t - 1]) ? 1 : 0);
        int isc = flag;
        #pragma unroll
        for (int d = 1; d < EBLK; d <<= 1) {
            const int up = __shfl_up(isc, d);
            if (t >= d) isc += up;
        }
        if (flag) segstart[isc - 1] = t;
        if (t == EBLK - 1) { snseg = isc; segstart[isc] = EBLK; }
    }
    __syncthreads();
    const int nseg = snseg;

    const int ei = t >> 2;
    const int q  = t & 3;
    const int e7 = ei & 7;
    const int r = sr[ei], c = sc[ei], e = se[ei];

    const float dx = coord[3 * r + 0] - coord[3 * c + 0];
    const float dy = coord[3 * r + 1] - coord[3 * c + 1];
    const float dz = coord[3 * r + 2] - coord[3 * c + 2];
    const float radial = dx * dx + dy * dy + dz * dz;
    const float2 ea = ((const float2*)eattr)[e];

    // ---- phase 1: acc16 = preR[r] + preC[c] + ext; silu; pack to tileh ----
    union { uint4 v[2]; uint_t a[8]; } R, C;
    {
        const uint4* pr = (const uint4*)(preR + (size_t)r * 32);
        const uint4* pc = (const uint4*)(preC + (size_t)c * 32);
        R.v[0] = pr[q * 2]; R.v[1] = pr[q * 2 + 1];
        C.v[0] = pc[q * 2]; C.v[1] = pc[q * 2 + 1];
    }
    float acc16[16];
    #pragma unroll
    for (int p = 0; p < 8; p++) {
        const half2v hr = u2h(R.a[p]);
        const half2v hc = u2h(C.a[p]);
        acc16[2 * p]     = (float)hr.x + (float)hc.x;
        acc16[2 * p + 1] = (float)hr.y + (float)hc.y;
    }
    {
        const float ext3[3] = {radial, ea.x, ea.y};
        #pragma unroll
        for (int x = 0; x < 3; x++) {
            const float v = ext3[x];
            const float* w = &sExtW[x * 64 + q * 16];
            #pragma unroll
            for (int j = 0; j < 16; j++) acc16[j] += v * w[j];
        }
    }
    #pragma unroll
    for (int j = 0; j < 16; j++) acc16[j] = silu(acc16[j]);
    {
        uint4 g0, g1;
        g0.x = h2u(pkrtz(acc16[0],  acc16[1]));  g0.y = h2u(pkrtz(acc16[2],  acc16[3]));
        g0.z = h2u(pkrtz(acc16[4],  acc16[5]));  g0.w = h2u(pkrtz(acc16[6],  acc16[7]));
        g1.x = h2u(pkrtz(acc16[8],  acc16[9]));  g1.y = h2u(pkrtz(acc16[10], acc16[11]));
        g1.z = h2u(pkrtz(acc16[12], acc16[13])); g1.w = h2u(pkrtz(acc16[14], acc16[15]));
        ((uint4*)tileh)[ei * 8 + ((q * 2) ^ e7)]     = g0;
        ((uint4*)tileh)[ei * 8 + ((q * 2 + 1) ^ e7)] = g1;
    }
    __syncthreads();

    // ---- MFMA identities ----
    const int lane = t & 63;
    const int wv   = t >> 6;            // wave id = M-tile id
    const int lrow = lane & 15;         // N index within tile / A-row selector
    const int lkg  = lane >> 4;         // k-group
    const int arow = wv * 16 + lrow;    // A row (edge) for fragments
    const int e7a  = arow & 7;

    // A-fragments of hid (both K-steps)
    U4H8 a0, a1;
    a0.u = ((const uint4*)tileh)[arow * 8 + (lkg ^ e7a)];
    a1.u = ((const uint4*)tileh)[arow * 8 + ((4 + lkg) ^ e7a)];

    // ---- W2 GEMM via MFMA: m = silu(hid @ W2 + b2) ----
    f32x4 accn[4];
    #pragma unroll
    for (int n = 0; n < 4; n++) {
        const float b = sB2[n * 16 + lrow];
        f32x4 v = {b, b, b, b};
        accn[n] = v;
    }
    #pragma unroll
    for (int n = 0; n < 4; n++) {
        const int bc = n * 16 + lrow;
        const int b7 = bc & 7;
        U4H8 b0, b1;
        b0.u = ((const uint4*)sWp)[bc * 8 + (lkg ^ b7)];
        b1.u = ((const uint4*)sWp)[bc * 8 + ((4 + lkg) ^ b7)];
        accn[n] = __builtin_amdgcn_mfma_f32_16x16x32_f16(a0.h, b0.h, accn[n], 0, 0, 0);
        accn[n] = __builtin_amdgcn_mfma_f32_16x16x32_f16(a1.h, b1.h, accn[n], 0, 0, 0);
    }
    __syncthreads();   // ALL W2 (sWp) + hid (tileh) reads done

    // ---- T14 write-late: cW1 reg->LDS (linear; layout pre-swizzled) ----
    ((uint4*)sWp)[t]       = cwr0;
    ((uint4*)sWp)[t + 256] = cwr1;
    // ---- silu(m) -> tileh (swizzled scatter, C/D layout) ----
    {
        ushort_t* th16 = (ushort_t*)tileh;
        const int mrow = wv * 16 + lkg * 4;
        #pragma unroll
        for (int n = 0; n < 4; n++) {
            const int ch = n * 16 + lrow;
            const int wi = ch >> 1;
            const int wg = wi >> 2, wj = wi & 3, hl = ch & 1;
            #pragma unroll
            for (int r2 = 0; r2 < 4; r2++) {
                const int edge = mrow + r2;
                th16[(edge * 32 + ((wg ^ (edge & 7)) << 2) + wj) * 2 + hl] =
                    f2hbits(silu(accn[n][r2]));
            }
        }
    }
    __syncthreads();   // m (tileh) + cW1 (sWp) visible

    // ---- cW1 GEMM via MFMA: chh = m @ cW1 + cb1; cw = silu(chh) @ cW2 ----
    U4H8 ma0, ma1;
    ma0.u = ((const uint4*)tileh)[arow * 8 + (lkg ^ e7a)];
    ma1.u = ((const uint4*)tileh)[arow * 8 + ((4 + lkg) ^ e7a)];
    f32x4 cacc[4];
    #pragma unroll
    for (int n = 0; n < 4; n++) {
        const float b = sCB1[n * 16 + lrow];
        f32x4 v = {b, b, b, b};
        cacc[n] = v;
    }
    #pragma unroll
    for (int n = 0; n < 4; n++) {
        const int bc = n * 16 + lrow;
        const int b7 = bc & 7;
        U4H8 b0, b1;
        b0.u = ((const uint4*)sWp)[bc * 8 + (lkg ^ b7)];
        b1.u = ((const uint4*)sWp)[bc * 8 + ((4 + lkg) ^ b7)];
        cacc[n] = __builtin_amdgcn_mfma_f32_16x16x32_f16(ma0.h, b0.h, cacc[n], 0, 0, 0);
        cacc[n] = __builtin_amdgcn_mfma_f32_16x16x32_f16(ma1.h, b1.h, cacc[n], 0, 0, 0);
    }
    // cw partial: sum over in-lane n-tiles, then butterfly over the 16 lanes
    float p0 = 0.f, p1 = 0.f, p2 = 0.f, p3 = 0.f;
    #pragma unroll
    for (int n = 0; n < 4; n++) {
        const float w2v = sCW2v[n * 16 + lrow];
        p0 += silu(cacc[n][0]) * w2v;
        p1 += silu(cacc[n][1]) * w2v;
        p2 += silu(cacc[n][2]) * w2v;
        p3 += silu(cacc[n][3]) * w2v;
    }
    #pragma unroll
    for (int m = 1; m <= 8; m <<= 1) {
        p0 += __shfl_xor(p0, m);
        p1 += __shfl_xor(p1, m);
        p2 += __shfl_xor(p2, m);
        p3 += __shfl_xor(p3, m);
    }
    if (lrow == 0) {
        const int mrow = wv * 16 + lkg * 4;
        scw[mrow + 0] = p0; scw[mrow + 1] = p1;
        scw[mrow + 2] = p2; scw[mrow + 3] = p3;
    }

    // ---- segmented reduction: magg (reads swizzled tileh m) ----
    for (int w = t; w < nseg * 64; w += 256) {
        const int lr2 = w >> 6, cc = w & 63;
        const int pp0 = segstart[lr2], pp1 = segstart[lr2 + 1];
        const int kp = cc >> 1, hi = cc & 1;
        const int kg = kp >> 2, kj = kp & 3;
        float s = 0.f;
        for (int p = pp0; p < pp1; p++) {
            const half2v h = u2h(tileh[p * 32 + ((kg ^ (p & 7)) << 2) + kj]);
            s += hi ? (float)h.y : (float)h.x;
        }
        atomicAdd(&magg[(size_t)sr[pp0] * 64 + cc], s);
    }
    __syncthreads();   // scw visible; all magg tileh reads done

    // ---- segmented reduction: csum ----
    const float cw = scw[ei];
    float* tf = (float*)tileh;
    if (q < 3) tf[ei * 4 + q] = (q == 0 ? dx : (q == 1 ? dy : dz)) * cw;
    __syncthreads();
    for (int w = t; w < nseg * 3; w += 256) {
        const int lr2 = w / 3, cc = w - 3 * lr2;
        const int pp0 = segstart[lr2], pp1 = segstart[lr2 + 1];
        float s = 0.f;
        for (int p = pp0; p < pp1; p++) s += tf[p * 4 + cc];
        atomicAdd(&csum[3 * sr[pp0] + cc], s);
    }
}

// ---- per-layer node kernel: wconv-staged weights (pure uint4 copies) ---------
__global__ __launch_bounds__(256, 2) void node_kernel(
    const uint_t* __restrict__ nwp,                 // wconv layer block (this layer)
    const uint_t* __restrict__ nwpn,                // wconv layer block (next layer)
    const float* __restrict__ gVB1, const float* __restrict__ gVW2,
    const float* __restrict__ gVB2,
    const float* __restrict__ gGB1, const float* __restrict__ gGW2,
    const float* __restrict__ gGB2,
    const float* __restrict__ gNB1,
    const float* __restrict__ gNW2, const float* __restrict__ gNB2,
    const float* __restrict__ gB1n,
    float* __restrict__ csum, const int* __restrict__ off,
    const float* __restrict__ vsrc, const float* __restrict__ field,
    float* __restrict__ magg,
    float* __restrict__ coord, float* __restrict__ hh,
    uint_t* __restrict__ preR, uint_t* __restrict__ preC, const int emit_pre)
{
    __shared__ __align__(16) uint_t sNW1p[4096];       // NW1 f16 pairs, 16 KB
    __shared__ __align__(16) uint_t sW1np[4096];       // next-layer W1 f16, 16 KB
    __shared__ __align__(16) uint_t sVW1p[2048];       // vW1 f16 pairs, 8 KB
    __shared__ __align__(16) uint_t sGW1p[2048];       // gW1 f16 pairs, 8 KB
    __shared__ __align__(16) float sNW2[4096];         // NW2 fp32, 16 KB
    __shared__ __align__(16) float tile[NPB2 * 136];   // hh[0..63], magg[68..131]
    __shared__ float sNB1[64], sNB2[64], sB1n[64];

    const int t = threadIdx.x;
    for (int i = t; i < 1024; i += 256)
        ((uint4*)sNW1p)[i] = ((const uint4*)(nwp + WC_NW1))[i];
    for (int i = t; i < 1024; i += 256)
        ((uint4*)sW1np)[i] = ((const uint4*)(nwpn + WC_EW1))[i];
    for (int i = t; i < 512; i += 256)
        ((uint4*)sVW1p)[i] = ((const uint4*)(nwp + WC_VW1))[i];
    for (int i = t; i < 512; i += 256)
        ((uint4*)sGW1p)[i] = ((const uint4*)(nwp + WC_GW1))[i];
    for (int i = t; i < 1024; i += 256)
        ((float4*)sNW2)[i] = ((const float4*)gNW2)[i];
    if (t < 64) { sNB1[t] = gNB1[t]; sNB2[t] = gNB2[t]; sB1n[t] = gB1n[t]; }

    const int ni = t >> 4;          // node in block (0..15)
    const int q  = t & 15;          // channel group (4 ch)
    const int n = blockIdx.x * NPB2 + ni;    // grid*NPB2 = 10000 exactly
    float* T = &tile[ni * 136];

    ((float4*)T)[q]        = ((const float4*)(hh + (size_t)n * 64))[q];
    ((float4*)(T + 68))[q] = ((const float4*)(magg + (size_t)n * 64))[q];
    __syncthreads();

    // ---- vw & gw fused: one T read per kp feeds 8 independent chains ----
    float v4[4], g4[4];
    {
        const float4 bv = ((const float4*)gVB1)[q];
        const float4 bg = ((const float4*)gGB1)[q];
        v4[0] = bv.x; v4[1] = bv.y; v4[2] = bv.z; v4[3] = bv.w;
        g4[0] = bg.x; g4[1] = bg.y; g4[2] = bg.z; g4[3] = bg.w;
    }
    #pragma unroll 8
    for (int kp = 0; kp < 32; kp++) {
        const half2v p = pkrtz(T[2 * kp], T[2 * kp + 1]);
        const uint4 wv = *(const uint4*)&sVW1p[kp * 64 + q * 4];
        const uint4 wg = *(const uint4*)&sGW1p[kp * 64 + q * 4];
        v4[0] = dot2h(p, wv.x, v4[0]); v4[1] = dot2h(p, wv.y, v4[1]);
        v4[2] = dot2h(p, wv.z, v4[2]); v4[3] = dot2h(p, wv.w, v4[3]);
        g4[0] = dot2h(p, wg.x, g4[0]); g4[1] = dot2h(p, wg.y, g4[1]);
        g4[2] = dot2h(p, wg.z, g4[2]); g4[3] = dot2h(p, wg.w, g4[3]);
    }
    float partv, partg;
    {
        const float4 wv2 = ((const float4*)gVW2)[q];
        const float4 wg2 = ((const float4*)gGW2)[q];
        partv = silu(v4[0]) * wv2.x + silu(v4[1]) * wv2.y
              + silu(v4[2]) * wv2.z + silu(v4[3]) * wv2.w;
        partg = silu(g4[0]) * wg2.x + silu(g4[1]) * wg2.y
              + silu(g4[2]) * wg2.z + silu(g4[3]) * wg2.w;
    }
    partv += __shfl_xor(partv, 1);  partg += __shfl_xor(partg, 1);
    partv += __shfl_xor(partv, 2);  partg += __shfl_xor(partg, 2);
    partv += __shfl_xor(partv, 4);  partg += __shfl_xor(partg, 4);
    partv += __shfl_xor(partv, 8);  partg += __shfl_xor(partg, 8);
    const float vw = partv + gVB2[0];
    const float gw = partg + gGB2[0];

    // ---- coord update (one thread per node) ----
    if (q == 0) {
        const float cn = fmaxf((float)(off[n + 1] - off[n]), 1.0f);
        #pragma unroll
        for (int d = 0; d < 3; d++)
            coord[3 * n + d] += csum[3 * n + d] / cn
                              + vw * vsrc[3 * n + d]
                              + gw * field[3 * n + d];
    }

    // ---- node MLP hidden: split hh/magg accumulator sets (8 chains) ----
    float aA[4], aB[4];
    {
        const float4 b = ((const float4*)sNB1)[q];
        aA[0] = b.x; aA[1] = b.y; aA[2] = b.z; aA[3] = b.w;
        aB[0] = aB[1] = aB[2] = aB[3] = 0.f;
    }
    #pragma unroll 8
    for (int kp = 0; kp < 32; kp++) {
        const half2v pA = pkrtz(T[2 * kp], T[2 * kp + 1]);
        const half2v pB = pkrtz(T[68 + 2 * kp], T[68 + 2 * kp + 1]);
        const uint4 wA = *(const uint4*)&sNW1p[kp * 64 + q * 4];
        const uint4 wB = *(const uint4*)&sNW1p[(32 + kp) * 64 + q * 4];
        aA[0] = dot2h(pA, wA.x, aA[0]); aA[1] = dot2h(pA, wA.y, aA[1]);
        aA[2] = dot2h(pA, wA.z, aA[2]); aA[3] = dot2h(pA, wA.w, aA[3]);
        aB[0] = dot2h(pB, wB.x, aB[0]); aB[1] = dot2h(pB, wB.y, aB[1]);
        aB[2] = dot2h(pB, wB.z, aB[2]); aB[3] = dot2h(pB, wB.w, aB[3]);
    }
    float a4[4];
    #pragma unroll
    for (int j = 0; j < 4; j++) a4[j] = silu(aA[j] + aB[j]);

    __syncthreads();
    {
        float4 v; v.x = a4[0]; v.y = a4[1]; v.z = a4[2]; v.w = a4[3];
        ((float4*)T)[q] = v;
    }
    __syncthreads();

    {
        float4 z; z.x = z.y = z.z = z.w = 0.f;
        ((float4*)(magg + (size_t)n * 64))[q] = z;
        if (q == 0) { csum[3 * n] = 0.f; csum[3 * n + 1] = 0.f; csum[3 * n + 2] = 0.f; }
    }

    // ---- output GEMM: even/odd kk accumulator split (8 chains) ----
    float oA[4], oB[4];
    {
        const float4 b = ((const float4*)sNB2)[q];
        oA[0] = b.x; oA[1] = b.y; oA[2] = b.z; oA[3] = b.w;
        oB[0] = oB[1] = oB[2] = oB[3] = 0.f;
    }
    #pragma unroll 4
    for (int kk = 0; kk < 8; kk++) {
        const float4 hA = ((const float4*)T)[2 * kk];
        const float4 hB = ((const float4*)T)[2 * kk + 1];
        const float avA[4] = {hA.x, hA.y, hA.z, hA.w};
        const float avB[4] = {hB.x, hB.y, hB.z, hB.w};
        #pragma unroll
        for (int u = 0; u < 4; u++) {
            const float vA = avA[u];
            const float vB = avB[u];
            const float4 wA = ((const float4*)(sNW2 + (8 * kk + u) * 64))[q];
            const float4 wB = ((const float4*)(sNW2 + (8 * kk + 4 + u) * 64))[q];
            oA[0] += vA * wA.x; oA[1] += vA * wA.y; oA[2] += vA * wA.z; oA[3] += vA * wA.w;
            oB[0] += vB * wB.x; oB[1] += vB * wB.y; oB[2] += vB * wB.z; oB[3] += vB * wB.w;
        }
    }
    float o4[4];
    #pragma unroll
    for (int j = 0; j < 4; j++) o4[j] = oA[j] + oB[j];
    {
        float4 v; v.x = o4[0]; v.y = o4[1]; v.z = o4[2]; v.w = o4[3];
        ((float4*)(hh + (size_t)n * 64))[q] = v;
    }

    // ---- fused pre emission for next layer ----
    if (emit_pre) {
        __syncthreads();
        {
            float4 v; v.x = o4[0]; v.y = o4[1]; v.z = o4[2]; v.w = o4[3];
            ((float4*)T)[q] = v;
        }
        __syncthreads();

        float aR[4], aC[4];
        {
            const float4 b = ((const float4*)sB1n)[q];
            aR[0] = b.x; aR[1] = b.y; aR[2] = b.z; aR[3] = b.w;
            aC[0] = aC[1] = aC[2] = aC[3] = 0.f;
        }
        #pragma unroll 8
        for (int kp = 0; kp < 32; kp++) {
            const half2v p = pkrtz(T[2 * kp], T[2 * kp + 1]);
            const uint4 wr = *(const uint4*)&sW1np[kp * 64 + q * 4];
            const uint4 wc = *(const uint4*)&sW1np[(32 + kp) * 64 + q * 4];
            aR[0] = dot2h(p, wr.x, aR[0]); aR[1] = dot2h(p, wr.y, aR[1]);
            aR[2] = dot2h(p, wr.z, aR[2]); aR[3] = dot2h(p, wr.w, aR[3]);
            aC[0] = dot2h(p, wc.x, aC[0]); aC[1] = dot2h(p, wc.y, aC[1]);
            aC[2] = dot2h(p, wc.z, aC[2]); aC[3] = dot2h(p, wc.w, aC[3]);
        }
        uint2 oR, oC;
        oR.x = h2u(pkrtz(aR[0], aR[1])); oR.y = h2u(pkrtz(aR[2], aR[3]));
        oC.x = h2u(pkrtz(aC[0], aC[1])); oC.y = h2u(pkrtz(aC[2], aC[3]));
        *(uint2*)(preR + (size_t)n * 32 + q * 2) = oR;
        *(uint2*)(preC + (size_t)n * 32 + q * 2) = oC;
    }
}

// ---- host launch -------------------------------------------------------------
extern "C" void kernel_launch(void* const* d_in, const int* in_sizes, int n_in,
                              void* d_out, int out_size, void* d_ws, size_t ws_size,
                              hipStream_t stream) {
    float* wsf = (float*)d_ws;
    int*   wsi = (int*)(wsf + 1340000);
    uint_t* preR  = (uint_t*)(wsi + IOFF_PRER);
    uint_t* preC  = (uint_t*)(wsi + IOFF_PREC);
    uint_t* wconv = (uint_t*)(wsi + IOFF_WCONV);
    float* coord = (float*)d_out;
    const int* edges = (const int*)d_in[4];
    const int* rows = edges;
    const int* cols = edges + NE;

    hipMemsetAsync(wsi + IOFF_CNTI, 0, NN * sizeof(int), stream);
    // weight pre-conversion (once per call; all 4 layers)
    wconv_kernel<<<NL, 256, 0, stream>>>(
        (const float*)d_in[15], (const float*)d_in[17], (const float*)d_in[23],
        (const float*)d_in[26], (const float*)d_in[30], (const float*)d_in[19],
        wconv);
    counti_kernel<<<(NE + 255) / 256, 256, 0, stream>>>(rows, wsi + IOFF_CNTI);
    scan_kernel<<<1, 1024, 0, stream>>>(wsi + IOFF_CNTI, wsi + IOFF_OFF, wsi + IOFF_CURSOR);
    scatter_kernel<<<(NE + 255) / 256, 256, 0, stream>>>(rows, wsi + IOFF_CURSOR,
                                                         wsi + IOFF_PERM);

    node_init<<<(NN + 255) / 256, 256, 0, stream>>>(
        (const float*)d_in[0], (const float*)d_in[1], (const float*)d_in[2],
        (const int*)d_in[5], (const float*)d_in[8],
        (const float*)d_in[9],  (const float*)d_in[10],
        (const float*)d_in[11], (const float*)d_in[12],
        (const float*)d_in[13], (const float*)d_in[14],
        (const float*)d_in[6],  (const float*)d_in[7],
        coord, wsf + OFF_FIELD, wsf + OFF_HH);

    // csum+magg zeroed once; node_kernel re-zeroes them each layer
    hipMemsetAsync(wsf + OFF_CSUM, 0, (30000 + 640000) * sizeof(float), stream);

    // layer-0 pre; layers 1..3 get pre from node_kernel's fused epilogue
    pre_kernel<<<NNODEBLK, 256, 0, stream>>>(
        wsf + OFF_HH,
        wconv + 0 * 16384 + WC_EW1, (const float*)d_in[16],
        preR, preC);

    for (int l = 0; l < NL; l++) {
        const int ln = (l + 1 < NL) ? (l + 1) : 0;   // next-layer W1 (unused if last)
        edge_kernel<<<NEBLK, 256, 0, stream>>>(
            rows, cols, wsi + IOFF_PERM,
            coord, (const float*)d_in[3],
            ((const float*)d_in[15]) + l * 8384,
            wconv + l * 16384,
            ((const float*)d_in[18]) + l * 64,
            ((const float*)d_in[24]) + l * 64,
            ((const float*)d_in[25]) + l * 64,
            preR, preC,
            wsf + OFF_CSUM, wsf + OFF_MAGG);
        node_kernel<<<NODEBLK2, 256, 0, stream>>>(
            wconv + l * 16384, wconv + ln * 16384,
            ((const float*)d_in[27]) + l * 64,
            ((const float*)d_in[28]) + l * 64,   ((const float*)d_in[29]) + l,
            ((const float*)d_in[31]) + l * 64,
            ((const float*)d_in[32]) + l * 64,   ((const float*)d_in[33]) + l,
            ((const float*)d_in[20]) + l * 64,
            ((const float*)d_in[21]) + l * 4096, ((const float*)d_in[22]) + l * 64,
            ((const float*)d_in[16]) + ln * 64,
            wsf + OFF_CSUM, wsi + IOFF_OFF, (const float*)d_in[2],
            wsf + OFF_FIELD, wsf + OFF_MAGG, coord, wsf + OFF_HH,
            preR, preC, (l + 1 < NL) ? 1 : 0);
    }
}

// Round 23
// 441.032 us; speedup vs baseline: 1.0560x; 1.0560x over previous
//
#include <hip/hip_runtime.h>
#include <hip/hip_bf16.h>

typedef unsigned short ushort_t;
typedef unsigned int uint_t;

#define NN    10000
#define NE    320000
#define NL    4
#define EBLK  64        // edges per block (4 threads per edge)
#define NEBLK 5000      // NE / EBLK exactly
#define NPB   64        // nodes per block in pre_kernel (4 threads per node)
#define NNODEBLK 157    // ceil(NN / NPB)
#define NPB2  16        // nodes per block in node_kernel (16 threads per node)
#define NODEBLK2 625    // NN / NPB2 exactly, no tail

// ---- workspace float offsets -------------------------------------------------
#define OFF_FIELD 0        // 30000
#define OFF_HH    30000    // 640000
#define OFF_CSUM  670000   // 30000  (contiguous with MAGG for one memset)
#define OFF_MAGG  700000   // 640000 -> float end 1340000
// ---- int region (starts at float offset 1340000) ----------------------------
#define IOFF_CNTI   0        // 10000
#define IOFF_OFF    10000    // 10001
#define IOFF_CURSOR 20001    // 10000
#define IOFF_PERM   30001    // 320000
#define IOFF_PRER   350004   // 320000 uints (f16-pair preR; 16B-aligned)
#define IOFF_PREC   670004   // 320000 uints
#define IOFF_WCONV  990004   // 4 layers x 22528 uints = 90112 -> int end 1080116
// total ws = (1340000 + 1080116) * 4 = 9,680,464 B
// per-layer wconv block of 22528 uints:
#define WC_EW1   0      // 4096  eW1 rows 0..127, pair-major kp*64+j (pre_kernel)
#define WC_EW2   4096   // 2048  eW2, swizzled channel-major (edge)
#define WC_CW1   6144   // 2048  cW1, swizzled channel-major (edge)
#define WC_VG    8192   // 4096  [vW1 ch0..63 | gW1 ch64..127], sw ch-major 32 pairs
#define WC_NW1S  12288  // 4096  nW1, sw ch-major 64 pairs (XOR ch&15)
#define WC_NW2S  16384  // 2048  nW2, sw ch-major 32 pairs
#define WC_EW1S  18432  // 4096  [W1r ch0..63 | W1c ch64..127], sw ch-major 32 pairs
#define WC_SIZE  22528

// fast silu: v_rcp_f32 instead of IEEE divide (~1e-7 rel err, VALU-bound paths)
__device__ __forceinline__ float silu(float x) {
    return x * __builtin_amdgcn_rcpf(1.0f + __expf(-x));
}

// ---- f16 pair helpers (clang builtins use __fp16 V2h / V8h) ------------------
typedef __fp16 half2v __attribute__((ext_vector_type(2)));
typedef __fp16 f16x8 __attribute__((ext_vector_type(8)));
typedef float f32x4 __attribute__((ext_vector_type(4)));
union U4H8 { uint4 u; f16x8 h; };
__device__ __forceinline__ half2v u2h(uint_t u) {
    union { uint_t u; half2v h; } x; x.u = u; return x.h;
}
__device__ __forceinline__ uint_t h2u(half2v h) {
    union { half2v h; uint_t u; } x; x.h = h; return x.u;
}
__device__ __forceinline__ half2v pkrtz(float a, float b) {
    return __builtin_amdgcn_cvt_pkrtz(a, b);
}
__device__ __forceinline__ float dot2h(half2v a, uint_t w, float c) {
#if __has_builtin(__builtin_amdgcn_fdot2)
    return __builtin_amdgcn_fdot2(a, u2h(w), c, false);
#else
    union { uint_t u; __fp16 h[2]; } x; x.u = w;
    return c + (float)a.x * (float)x.h[0] + (float)a.y * (float)x.h[1];
#endif
}
__device__ __forceinline__ ushort_t f2hbits(float f) {
    union { __fp16 h; ushort_t u; } x; x.h = (__fp16)f; return x.u;
}

// ---- weight pre-conversion: fp32 -> f16-pair formats, once per call ----------
__global__ __launch_bounds__(256) void wconv_kernel(
    const float* __restrict__ eW1, const float* __restrict__ eW2,
    const float* __restrict__ cW1, const float* __restrict__ vW1,
    const float* __restrict__ gW1, const float* __restrict__ nW1,
    const float* __restrict__ nW2,
    uint_t* __restrict__ out)
{
    const int l = blockIdx.x;
    const int t = threadIdx.x;
    uint_t* o = out + l * WC_SIZE;
    const float* e1 = eW1 + l * 8384;
    const float* e2 = eW2 + l * 4096;
    const float* c1 = cW1 + l * 4096;
    const float* v1 = vW1 + l * 4096;
    const float* g1 = gW1 + l * 4096;
    const float* n1 = nW1 + l * 8192;
    const float* n2 = nW2 + l * 4096;

    for (int i = t; i < 4096; i += 256)        // eW1 rows 0..127, pair-major
        o[WC_EW1 + i] = h2u(pkrtz(e1[(i >> 6) * 128 + (i & 63)],
                                  e1[(i >> 6) * 128 + 64 + (i & 63)]));
    for (int i = t; i < 2048; i += 256) {      // eW2 swizzled channel-major
        const int kp = i >> 6, bc = i & 63;
        const uint_t v = h2u(pkrtz(e2[kp * 128 + bc], e2[kp * 128 + 64 + bc]));
        o[WC_EW2 + bc * 32 + (((kp >> 2) ^ (bc & 7)) << 2) + (kp & 3)] = v;
    }
    for (int i = t; i < 2048; i += 256) {      // cW1 swizzled channel-major
        const int kp = i >> 6, bc = i & 63;
        const uint_t v = h2u(pkrtz(c1[kp * 128 + bc], c1[kp * 128 + 64 + bc]));
        o[WC_CW1 + bc * 32 + (((kp >> 2) ^ (bc & 7)) << 2) + (kp & 3)] = v;
    }
    for (int i = t; i < 2048; i += 256) {      // vW1 -> VG ch 0..63
        const int kp = i >> 6, ch = i & 63;
        const uint_t v = h2u(pkrtz(v1[kp * 128 + ch], v1[kp * 128 + 64 + ch]));
        o[WC_VG + ch * 32 + (((kp >> 2) ^ (ch & 7)) << 2) + (kp & 3)] = v;
    }
    for (int i = t; i < 2048; i += 256) {      // gW1 -> VG ch 64..127
        const int kp = i >> 6, ch = i & 63;
        const uint_t v = h2u(pkrtz(g1[kp * 128 + ch], g1[kp * 128 + 64 + ch]));
        o[WC_VG + (64 + ch) * 32 + (((kp >> 2) ^ (ch & 7)) << 2) + (kp & 3)] = v;
    }
    for (int i = t; i < 4096; i += 256) {      // nW1: 64 ch x 64 pairs, XOR ch&15
        const int kp = i >> 6, ch = i & 63;    // kp 0..63
        const uint_t v = h2u(pkrtz(n1[kp * 128 + ch], n1[kp * 128 + 64 + ch]));
        o[WC_NW1S + ch * 64 + (((kp >> 2) ^ (ch & 15)) << 2) + (kp & 3)] = v;
    }
    for (int i = t; i < 2048; i += 256) {      // nW2: 64 ch x 32 pairs
        const int kp = i >> 6, ch = i & 63;
        const uint_t v = h2u(pkrtz(n2[kp * 128 + ch], n2[kp * 128 + 64 + ch]));
        o[WC_NW2S + ch * 32 + (((kp >> 2) ^ (ch & 7)) << 2) + (kp & 3)] = v;
    }
    for (int i = t; i < 2048; i += 256) {      // W1r (eW1 rows 0..63) -> EW1S ch 0..63
        const int kp = i >> 6, ch = i & 63;
        const uint_t v = h2u(pkrtz(e1[kp * 128 + ch], e1[kp * 128 + 64 + ch]));
        o[WC_EW1S + ch * 32 + (((kp >> 2) ^ (ch & 7)) << 2) + (kp & 3)] = v;
    }
    for (int i = t; i < 2048; i += 256) {      // W1c (eW1 rows 64..127) -> ch 64..127
        const int kp = i >> 6, ch = i & 63;
        const uint_t v = h2u(pkrtz(e1[(64 + 2 * kp) * 64 + ch],
                                   e1[(64 + 2 * kp + 1) * 64 + ch]));
        o[WC_EW1S + (64 + ch) * 32 + (((kp >> 2) ^ (ch & 7)) << 2) + (kp & 3)] = v;
    }
}

// ---- CSR build: per-row int counts ------------------------------------------
__global__ __launch_bounds__(256) void counti_kernel(const int* __restrict__ rows,
                                                     int* __restrict__ cnti) {
    const int e = blockIdx.x * 256 + threadIdx.x;
    if (e < NE) {
        int r = rows[e];
        r = ((uint_t)r < (uint_t)NN) ? r : 0;
        atomicAdd(&cnti[r], 1);
    }
}

// ---- CSR build: exclusive scan over 10000 counts (single block) --------------
__global__ __launch_bounds__(1024) void scan_kernel(const int* __restrict__ cnti,
                                                    int* __restrict__ off,
                                                    int* __restrict__ cursor) {
    __shared__ int part[1024];
    const int t = threadIdx.x;
    const int base = t * 10;
    int loc[10];
    int s = 0;
    #pragma unroll
    for (int i = 0; i < 10; i++) {
        const int idx = base + i;
        const int v = (idx < NN) ? cnti[idx] : 0;
        loc[i] = s; s += v;
    }
    part[t] = s;
    __syncthreads();
    const int own = s;
    for (int d = 1; d < 1024; d <<= 1) {
        const int v = (t >= d) ? part[t - d] : 0;
        __syncthreads();
        part[t] += v;
        __syncthreads();
    }
    const int excl = part[t] - own;
    #pragma unroll
    for (int i = 0; i < 10; i++) {
        const int idx = base + i;
        if (idx < NN) { const int o = excl + loc[i]; off[idx] = o; cursor[idx] = o; }
    }
    if (t == 0) off[NN] = NE;
}

// ---- CSR build: scatter edge ids into row-sorted order -----------------------
__global__ __launch_bounds__(256) void scatter_kernel(const int* __restrict__ rows,
                                                      int* __restrict__ cursor,
                                                      int* __restrict__ perm) {
    const int e = blockIdx.x * 256 + threadIdx.x;
    if (e < NE) {
        int r = rows[e];
        r = ((uint_t)r < (uint_t)NN) ? r : 0;
        const int pos = atomicAdd(&cursor[r], 1);
        if ((uint_t)pos < (uint_t)NE) perm[pos] = e;
    }
}

// ---- field network + node embedding + coord init (once per call) ------------
__global__ __launch_bounds__(256) void node_init(
    const float* __restrict__ hsrc, const float* __restrict__ xsrc,
    const float* __restrict__ vsrc, const int* __restrict__ charges,
    const float* __restrict__ cls,
    const float* __restrict__ fW1, const float* __restrict__ fb1,
    const float* __restrict__ fW2, const float* __restrict__ fb2,
    const float* __restrict__ fW3, const float* __restrict__ fb3,
    const float* __restrict__ embW, const float* __restrict__ embb,
    float* __restrict__ coord, float* __restrict__ field, float* __restrict__ hh)
{
    __shared__ float sFW1[704], sFW2[1024], sFW3[96];
    __shared__ float sFB1[32], sFB2[32], sFB3[3], sCLS[32], sEW[64], sEB[64];
    const int t = threadIdx.x;
    for (int i = t; i < 704; i += 256) sFW1[i] = fW1[i];
    for (int i = t; i < 1024; i += 256) sFW2[i] = fW2[i];
    if (t < 96) sFW3[t] = fW3[t];
    if (t < 32) { sFB1[t] = fb1[t]; sFB2[t] = fb2[t]; sCLS[t] = cls[t]; }
    if (t < 3)  sFB3[t] = fb3[t];
    if (t < 64) { sEW[t] = embW[t]; sEB[t] = embb[t]; }
    __syncthreads();

    const int n = blockIdx.x * 256 + t;
    if (n >= NN) return;

    float fin[22];
    #pragma unroll
    for (int d = 0; d < 3; d++) {
        fin[d]     = xsrc[3 * n + d];
        fin[3 + d] = vsrc[3 * n + d];
        coord[3 * n + d] = fin[d];
    }
    int ci = charges[n];
    ci = ((uint_t)ci < 2u) ? ci : 0;
    const int cix = ci * 16;
    #pragma unroll
    for (int k = 0; k < 16; k++) fin[6 + k] = sCLS[cix + k];

    float h1[32];
    #pragma unroll
    for (int j = 0; j < 32; j++) h1[j] = sFB1[j];
    #pragma unroll
    for (int k = 0; k < 22; k++) {
        const float v = fin[k];
        #pragma unroll
        for (int j = 0; j < 32; j++) h1[j] += v * sFW1[k * 32 + j];
    }
    #pragma unroll
    for (int j = 0; j < 32; j++) h1[j] = silu(h1[j]);

    float h2[32];
    #pragma unroll
    for (int j = 0; j < 32; j++) h2[j] = sFB2[j];
    #pragma unroll
    for (int k = 0; k < 32; k++) {
        const float v = h1[k];
        #pragma unroll
        for (int j = 0; j < 32; j++) h2[j] += v * sFW2[k * 32 + j];
    }
    #pragma unroll
    for (int j = 0; j < 32; j++) h2[j] = silu(h2[j]);

    #pragma unroll
    for (int d = 0; d < 3; d++) {
        float s = sFB3[d];
        #pragma unroll
        for (int j = 0; j < 32; j++) s += h2[j] * sFW3[j * 3 + d];
        field[3 * n + d] = s;
    }

    const float hv = hsrc[n];
    #pragma unroll
    for (int j = 0; j < 64; j++) hh[(size_t)n * 64 + j] = hv * sEW[j] + sEB[j];
}

// ---- layer-0 pre kernel (staging a uint4 copy from wconv; r22-validated) -----
__global__ __launch_bounds__(256, 4) void pre_kernel(
    const float* __restrict__ hh,
    const uint_t* __restrict__ w1p, const float* __restrict__ gEB1,
    uint_t* __restrict__ preR, uint_t* __restrict__ preC)
{
    __shared__ __align__(16) uint_t sW1p[4096];
    __shared__ float sB1[64];
    const int t = threadIdx.x;
    for (int i = t; i < 1024; i += 256)
        ((uint4*)sW1p)[i] = ((const uint4*)w1p)[i];
    if (t < 64) sB1[t] = gEB1[t];
    __syncthreads();

    const int ni = t >> 2, q = t & 3;
    int n = blockIdx.x * NPB + ni;
    const bool valid = (n < NN);
    n = valid ? n : (NN - 1);
    const float4* h4p = (const float4*)(hh + (size_t)n * 64);

    float acc[16];
    #pragma unroll
    for (int j = 0; j < 16; j++) acc[j] = sB1[q * 16 + j];
    #pragma unroll
    for (int kk = 0; kk < 16; kk++) {
        const float4 a = h4p[kk];
        const half2v p0 = pkrtz(a.x, a.y);
        const half2v p1 = pkrtz(a.z, a.w);
        const uint4* w0 = (const uint4*)&sW1p[(2 * kk) * 64 + q * 16];
        const uint4* w1 = (const uint4*)&sW1p[(2 * kk + 1) * 64 + q * 16];
        #pragma unroll
        for (int j4 = 0; j4 < 4; j4++) {
            const uint4 wa = w0[j4], wb = w1[j4];
            acc[4*j4+0] = dot2h(p1, wb.x, dot2h(p0, wa.x, acc[4*j4+0]));
            acc[4*j4+1] = dot2h(p1, wb.y, dot2h(p0, wa.y, acc[4*j4+1]));
            acc[4*j4+2] = dot2h(p1, wb.z, dot2h(p0, wa.z, acc[4*j4+2]));
            acc[4*j4+3] = dot2h(p1, wb.w, dot2h(p0, wa.w, acc[4*j4+3]));
        }
    }
    if (valid) {
        uint4 o0, o1;
        o0.x = h2u(pkrtz(acc[0],  acc[1]));  o0.y = h2u(pkrtz(acc[2],  acc[3]));
        o0.z = h2u(pkrtz(acc[4],  acc[5]));  o0.w = h2u(pkrtz(acc[6],  acc[7]));
        o1.x = h2u(pkrtz(acc[8],  acc[9]));  o1.y = h2u(pkrtz(acc[10], acc[11]));
        o1.z = h2u(pkrtz(acc[12], acc[13])); o1.w = h2u(pkrtz(acc[14], acc[15]));
        uint4* dst = (uint4*)(preR + (size_t)n * 32 + q * 8);
        dst[0] = o0; dst[1] = o1;
    }

    #pragma unroll
    for (int j = 0; j < 16; j++) acc[j] = 0.f;
    #pragma unroll
    for (int kk = 0; kk < 16; kk++) {
        const float4 a = h4p[kk];
        const half2v p0 = pkrtz(a.x, a.y);
        const half2v p1 = pkrtz(a.z, a.w);
        const uint4* w0 = (const uint4*)&sW1p[(32 + 2 * kk) * 64 + q * 16];
        const uint4* w1 = (const uint4*)&sW1p[(33 + 2 * kk) * 64 + q * 16];
        #pragma unroll
        for (int j4 = 0; j4 < 4; j4++) {
            const uint4 wa = w0[j4], wb = w1[j4];
            acc[4*j4+0] = dot2h(p1, wb.x, dot2h(p0, wa.x, acc[4*j4+0]));
            acc[4*j4+1] = dot2h(p1, wb.y, dot2h(p0, wa.y, acc[4*j4+1]));
            acc[4*j4+2] = dot2h(p1, wb.z, dot2h(p0, wa.z, acc[4*j4+2]));
            acc[4*j4+3] = dot2h(p1, wb.w, dot2h(p0, wa.w, acc[4*j4+3]));
        }
    }
    if (valid) {
        uint4 o0, o1;
        o0.x = h2u(pkrtz(acc[0],  acc[1]));  o0.y = h2u(pkrtz(acc[2],  acc[3]));
        o0.z = h2u(pkrtz(acc[4],  acc[5]));  o0.w = h2u(pkrtz(acc[6],  acc[7]));
        o1.x = h2u(pkrtz(acc[8],  acc[9]));  o1.y = h2u(pkrtz(acc[10], acc[11]));
        o1.z = h2u(pkrtz(acc[12], acc[13])); o1.w = h2u(pkrtz(acc[14], acc[15]));
        uint4* dst = (uint4*)(preC + (size_t)n * 32 + q * 8);
        dst[0] = o0; dst[1] = o1;
    }
}

// ---- per-layer edge kernel (byte-identical to round 22: 43.4us validated) ----
__global__ __launch_bounds__(256, 8) void edge_kernel(
    const int* __restrict__ rows, const int* __restrict__ cols,
    const int* __restrict__ perm,
    const float* __restrict__ coord,
    const float* __restrict__ eattr,
    const float* __restrict__ gEW1,                 // only ext rows 128..130
    const uint_t* __restrict__ ewp,                 // wconv layer block
    const float* __restrict__ gEB2,
    const float* __restrict__ gCB1, const float* __restrict__ gCW2,
    const uint_t* __restrict__ preR, const uint_t* __restrict__ preC,
    float* __restrict__ csum, float* __restrict__ magg)
{
    __shared__ __align__(16) uint_t tileh[EBLK * 32];
    __shared__ __align__(16) uint_t sWp[2048];
    __shared__ float sExtW[3 * 64];
    __shared__ float sB2[64], sCB1[64], sCW2v[64];
    __shared__ float scw[EBLK];
    __shared__ int   sr[EBLK], sc[EBLK], se[EBLK];
    __shared__ int   segstart[EBLK + 1];
    __shared__ int   snseg;

    const int t = threadIdx.x;
    const int bid = blockIdx.x;
    const int lb  = (bid & 7) * (NEBLK / 8) + (bid >> 3);

    const uint4 cwr0 = ((const uint4*)(ewp + WC_CW1))[t];
    const uint4 cwr1 = ((const uint4*)(ewp + WC_CW1))[t + 256];

    for (int i = t; i < 512; i += 256)
        ((uint4*)sWp)[i] = ((const uint4*)(ewp + WC_EW2))[i];
    if (t < 192) sExtW[t] = gEW1[8192 + t];
    if (t < 64) { sB2[t] = gEB2[t]; sCB1[t] = gCB1[t]; sCW2v[t] = gCW2[t]; }

    if (t < EBLK) {
        int e = perm[lb * EBLK + t];
        e = ((uint_t)e < (uint_t)NE) ? e : 0;
        int r = rows[e], c = cols[e];
        r = ((uint_t)r < (uint_t)NN) ? r : 0;
        c = ((uint_t)c < (uint_t)NN) ? c : 0;
        se[t] = e; sr[t] = r; sc[t] = c;
    }
    __syncthreads();

    if (t < EBLK) {
        const int flag = (t == 0) ? 1 : ((sr[t] != sr[t - 1]) ? 1 : 0);
        int isc = flag;
        #pragma unroll
        for (int d = 1; d < EBLK; d <<= 1) {
            const int up = __shfl_up(isc, d);
            if (t >= d) isc += up;
        }
        if (flag) segstart[isc - 1] = t;
        if (t == EBLK - 1) { snseg = isc; segstart[isc] = EBLK; }
    }
    __syncthreads();
    const int nseg = snseg;

    const int ei = t >> 2;
    const int q  = t & 3;
    const int e7 = ei & 7;
    const int r = sr[ei], c = sc[ei], e = se[ei];

    const float dx = coord[3 * r + 0] - coord[3 * c + 0];
    const float dy = coord[3 * r + 1] - coord[3 * c + 1];
    const float dz = coord[3 * r + 2] - coord[3 * c + 2];
    const float radial = dx * dx + dy * dy + dz * dz;
    const float2 ea = ((const float2*)eattr)[e];

    union { uint4 v[2]; uint_t a[8]; } R, C;
    {
        const uint4* pr = (const uint4*)(preR + (size_t)r * 32);
        const uint4* pc = (const uint4*)(preC + (size_t)c * 32);
        R.v[0] = pr[q * 2]; R.v[1] = pr[q * 2 + 1];
        C.v[0] = pc[q * 2]; C.v[1] = pc[q * 2 + 1];
    }
    float acc16[16];
    #pragma unroll
    for (int p = 0; p < 8; p++) {
        const half2v hr = u2h(R.a[p]);
        const half2v hc = u2h(C.a[p]);
        acc16[2 * p]     = (float)hr.x + (float)hc.x;
        acc16[2 * p + 1] = (float)hr.y + (float)hc.y;
    }
    {
        const float ext3[3] = {radial, ea.x, ea.y};
        #pragma unroll
        for (int x = 0; x < 3; x++) {
            const float v = ext3[x];
            const float* w = &sExtW[x * 64 + q * 16];
            #pragma unroll
            for (int j = 0; j < 16; j++) acc16[j] += v * w[j];
        }
    }
    #pragma unroll
    for (int j = 0; j < 16; j++) acc16[j] = silu(acc16[j]);
    {
        uint4 g0, g1;
        g0.x = h2u(pkrtz(acc16[0],  acc16[1]));  g0.y = h2u(pkrtz(acc16[2],  acc16[3]));
        g0.z = h2u(pkrtz(acc16[4],  acc16[5]));  g0.w = h2u(pkrtz(acc16[6],  acc16[7]));
        g1.x = h2u(pkrtz(acc16[8],  acc16[9]));  g1.y = h2u(pkrtz(acc16[10], acc16[11]));
        g1.z = h2u(pkrtz(acc16[12], acc16[13])); g1.w = h2u(pkrtz(acc16[14], acc16[15]));
        ((uint4*)tileh)[ei * 8 + ((q * 2) ^ e7)]     = g0;
        ((uint4*)tileh)[ei * 8 + ((q * 2 + 1) ^ e7)] = g1;
    }
    __syncthreads();

    const int lane = t & 63;
    const int wv   = t >> 6;
    const int lrow = lane & 15;
    const int lkg  = lane >> 4;
    const int arow = wv * 16 + lrow;
    const int e7a  = arow & 7;

    U4H8 a0, a1;
    a0.u = ((const uint4*)tileh)[arow * 8 + (lkg ^ e7a)];
    a1.u = ((const uint4*)tileh)[arow * 8 + ((4 + lkg) ^ e7a)];

    f32x4 accn[4];
    #pragma unroll
    for (int n = 0; n < 4; n++) {
        const float b = sB2[n * 16 + lrow];
        f32x4 v = {b, b, b, b};
        accn[n] = v;
    }
    #pragma unroll
    for (int n = 0; n < 4; n++) {
        const int bc = n * 16 + lrow;
        const int b7 = bc & 7;
        U4H8 b0, b1;
        b0.u = ((const uint4*)sWp)[bc * 8 + (lkg ^ b7)];
        b1.u = ((const uint4*)sWp)[bc * 8 + ((4 + lkg) ^ b7)];
        accn[n] = __builtin_amdgcn_mfma_f32_16x16x32_f16(a0.h, b0.h, accn[n], 0, 0, 0);
        accn[n] = __builtin_amdgcn_mfma_f32_16x16x32_f16(a1.h, b1.h, accn[n], 0, 0, 0);
    }
    __syncthreads();

    ((uint4*)sWp)[t]       = cwr0;
    ((uint4*)sWp)[t + 256] = cwr1;
    {
        ushort_t* th16 = (ushort_t*)tileh;
        const int mrow = wv * 16 + lkg * 4;
        #pragma unroll
        for (int n = 0; n < 4; n++) {
            const int ch = n * 16 + lrow;
            const int wi = ch >> 1;
            const int wg = wi >> 2, wj = wi & 3, hl = ch & 1;
            #pragma unroll
            for (int r2 = 0; r2 < 4; r2++) {
                const int edge = mrow + r2;
                th16[(edge * 32 + ((wg ^ (edge & 7)) << 2) + wj) * 2 + hl] =
                    f2hbits(silu(accn[n][r2]));
            }
        }
    }
    __syncthreads();

    U4H8 ma0, ma1;
    ma0.u = ((const uint4*)tileh)[arow * 8 + (lkg ^ e7a)];
    ma1.u = ((const uint4*)tileh)[arow * 8 + ((4 + lkg) ^ e7a)];
    f32x4 cacc[4];
    #pragma unroll
    for (int n = 0; n < 4; n++) {
        const float b = sCB1[n * 16 + lrow];
        f32x4 v = {b, b, b, b};
        cacc[n] = v;
    }
    #pragma unroll
    for (int n = 0; n < 4; n++) {
        const int bc = n * 16 + lrow;
        const int b7 = bc & 7;
        U4H8 b0, b1;
        b0.u = ((const uint4*)sWp)[bc * 8 + (lkg ^ b7)];
        b1.u = ((const uint4*)sWp)[bc * 8 + ((4 + lkg) ^ b7)];
        cacc[n] = __builtin_amdgcn_mfma_f32_16x16x32_f16(ma0.h, b0.h, cacc[n], 0, 0, 0);
        cacc[n] = __builtin_amdgcn_mfma_f32_16x16x32_f16(ma1.h, b1.h, cacc[n], 0, 0, 0);
    }
    float p0 = 0.f, p1 = 0.f, p2 = 0.f, p3 = 0.f;
    #pragma unroll
    for (int n = 0; n < 4; n++) {
        const float w2v = sCW2v[n * 16 + lrow];
        p0 += silu(cacc[n][0]) * w2v;
        p1 += silu(cacc[n][1]) * w2v;
        p2 += silu(cacc[n][2]) * w2v;
        p3 += silu(cacc[n][3]) * w2v;
    }
    #pragma unroll
    for (int m = 1; m <= 8; m <<= 1) {
        p0 += __shfl_xor(p0, m);
        p1 += __shfl_xor(p1, m);
        p2 += __shfl_xor(p2, m);
        p3 += __shfl_xor(p3, m);
    }
    if (lrow == 0) {
        const int mrow = wv * 16 + lkg * 4;
        scw[mrow + 0] = p0; scw[mrow + 1] = p1;
        scw[mrow + 2] = p2; scw[mrow + 3] = p3;
    }

    for (int w = t; w < nseg * 64; w += 256) {
        const int lr2 = w >> 6, cc = w & 63;
        const int pp0 = segstart[lr2], pp1 = segstart[lr2 + 1];
        const int kp = cc >> 1, hi = cc & 1;
        const int kg = kp >> 2, kj = kp & 3;
        float s = 0.f;
        for (int p = pp0; p < pp1; p++) {
            const half2v h = u2h(tileh[p * 32 + ((kg ^ (p & 7)) << 2) + kj]);
            s += hi ? (float)h.y : (float)h.x;
        }
        atomicAdd(&magg[(size_t)sr[pp0] * 64 + cc], s);
    }
    __syncthreads();

    const float cw = scw[ei];
    float* tf = (float*)tileh;
    if (q < 3) tf[ei * 4 + q] = (q == 0 ? dx : (q == 1 ? dy : dz)) * cw;
    __syncthreads();
    for (int w = t; w < nseg * 3; w += 256) {
        const int lr2 = w / 3, cc = w - 3 * lr2;
        const int pp0 = segstart[lr2], pp1 = segstart[lr2 + 1];
        float s = 0.f;
        for (int p = pp0; p < pp1; p++) s += tf[p * 4 + cc];
        atomicAdd(&csum[3 * sr[pp0] + cc], s);
    }
}

// ---- per-layer node kernel: full MFMA (16 nodes = 1 M-tile, wave = N-tile) ---
// vw/gw: 4 MFMA + cross-wave LDS combine; NW1: 4 MFMA; NW2: 2 MFMA; pre: 4.
// Fragment algebra identical to the r20/r21-verified edge patterns.
__global__ __launch_bounds__(256, 2) void node_kernel(
    const uint_t* __restrict__ nwp, const uint_t* __restrict__ nwpn,
    const float* __restrict__ gVB1, const float* __restrict__ gVW2,
    const float* __restrict__ gVB2,
    const float* __restrict__ gGB1, const float* __restrict__ gGW2,
    const float* __restrict__ gGB2,
    const float* __restrict__ gNB1, const float* __restrict__ gNB2,
    const float* __restrict__ gB1n,
    float* __restrict__ csum, const int* __restrict__ off,
    const float* __restrict__ vsrc, const float* __restrict__ field,
    float* __restrict__ magg,
    float* __restrict__ coord, float* __restrict__ hh,
    uint_t* __restrict__ preR, uint_t* __restrict__ preC, const int emit_pre)
{
    __shared__ __align__(16) uint_t sVG[4096];     // [128 ch][32 pairs] sw, 16 KB
    __shared__ __align__(16) uint_t sNW1S[4096];   // [64 ch][64 pairs] sw, 16 KB
    __shared__ __align__(16) uint_t sNW2S[2048];   // [64 ch][32 pairs] sw, 8 KB
    __shared__ __align__(16) uint_t sW1nS[4096];   // [128 ch][32 pairs] sw, 16 KB
    __shared__ __align__(16) uint_t tileA[1024];   // [16 nodes][64 pairs], 4 KB
    __shared__ __align__(16) uint_t tileM[512];    // [16 nodes][32 pairs], 2 KB
    __shared__ float pV[64], pG[64];               // [wave][16 nodes]
    __shared__ float sVB1[64], sGB1[64], sVW2[64], sGW2[64];
    __shared__ float sNB1[64], sNB2[64], sB1n[64];

    const int t = threadIdx.x;
    for (int i = t; i < 1024; i += 256) ((uint4*)sVG)[i]   = ((const uint4*)(nwp + WC_VG))[i];
    for (int i = t; i < 1024; i += 256) ((uint4*)sNW1S)[i] = ((const uint4*)(nwp + WC_NW1S))[i];
    for (int i = t; i < 512;  i += 256) ((uint4*)sNW2S)[i] = ((const uint4*)(nwp + WC_NW2S))[i];
    for (int i = t; i < 1024; i += 256) ((uint4*)sW1nS)[i] = ((const uint4*)(nwpn + WC_EW1S))[i];
    if (t < 64) { sVB1[t] = gVB1[t]; sGB1[t] = gGB1[t];
                  sVW2[t] = gVW2[t]; sGW2[t] = gGW2[t];
                  sNB1[t] = gNB1[t]; sNB2[t] = gNB2[t]; sB1n[t] = gB1n[t]; }

    const int ni = t >> 4, q = t & 15;
    const int nb = blockIdx.x * NPB2;
    const int n  = nb + ni;

    // ---- stage tileA: f16 pairs of [hh(L 0..7) || magg(L 8..15)] ----
    {
        const float4* src = (q < 8) ? (const float4*)(hh + (size_t)n * 64)
                                    : (const float4*)(magg + (size_t)n * 64);
        const int qq = q & 7;
        const float4 f0 = src[2 * qq], f1 = src[2 * qq + 1];
        uint4 u;
        u.x = h2u(pkrtz(f0.x, f0.y)); u.y = h2u(pkrtz(f0.z, f0.w));
        u.z = h2u(pkrtz(f1.x, f1.y)); u.w = h2u(pkrtz(f1.z, f1.w));
        ((uint4*)tileA)[ni * 16 + (q ^ ni)] = u;
    }
    __syncthreads();

    // ---- MFMA identities ----
    const int lane = t & 63, wv = t >> 6;
    const int lrow = lane & 15, lkg = lane >> 4;
    const int ch = wv * 16 + lrow;          // this wave's N-channel
    const int ch7 = ch & 7, ch15 = ch & 15;

    // A fragments over K=128 (node = lrow)
    U4H8 aA0, aA1, aA2, aA3;
    aA0.u = ((const uint4*)tileA)[lrow * 16 + ((0 + lkg) ^ lrow)];
    aA1.u = ((const uint4*)tileA)[lrow * 16 + ((4 + lkg) ^ lrow)];
    aA2.u = ((const uint4*)tileA)[lrow * 16 + ((8 + lkg) ^ lrow)];
    aA3.u = ((const uint4*)tileA)[lrow * 16 + ((12 + lkg) ^ lrow)];

    // ---- vw/gw GEMMs (K=64, hh half) ----
    f32x4 accV, accG;
    { const float b = sVB1[ch]; f32x4 v = {b, b, b, b}; accV = v; }
    { const float b = sGB1[ch]; f32x4 v = {b, b, b, b}; accG = v; }
    {
        U4H8 bv0, bv1, bg0, bg1;
        bv0.u = ((const uint4*)sVG)[ch * 8 + (lkg ^ ch7)];
        bv1.u = ((const uint4*)sVG)[ch * 8 + ((4 + lkg) ^ ch7)];
        bg0.u = ((const uint4*)sVG)[(64 + ch) * 8 + (lkg ^ ch7)];
        bg1.u = ((const uint4*)sVG)[(64 + ch) * 8 + ((4 + lkg) ^ ch7)];
        accV = __builtin_amdgcn_mfma_f32_16x16x32_f16(aA0.h, bv0.h, accV, 0, 0, 0);
        accV = __builtin_amdgcn_mfma_f32_16x16x32_f16(aA1.h, bv1.h, accV, 0, 0, 0);
        accG = __builtin_amdgcn_mfma_f32_16x16x32_f16(aA0.h, bg0.h, accG, 0, 0, 0);
        accG = __builtin_amdgcn_mfma_f32_16x16x32_f16(aA1.h, bg1.h, accG, 0, 0, 0);
    }
    {
        float pv0 = silu(accV[0]) * sVW2[ch], pv1 = silu(accV[1]) * sVW2[ch];
        float pv2 = silu(accV[2]) * sVW2[ch], pv3 = silu(accV[3]) * sVW2[ch];
        float pg0 = silu(accG[0]) * sGW2[ch], pg1 = silu(accG[1]) * sGW2[ch];
        float pg2 = silu(accG[2]) * sGW2[ch], pg3 = silu(accG[3]) * sGW2[ch];
        #pragma unroll
        for (int m = 1; m <= 8; m <<= 1) {
            pv0 += __shfl_xor(pv0, m); pv1 += __shfl_xor(pv1, m);
            pv2 += __shfl_xor(pv2, m); pv3 += __shfl_xor(pv3, m);
            pg0 += __shfl_xor(pg0, m); pg1 += __shfl_xor(pg1, m);
            pg2 += __shfl_xor(pg2, m); pg3 += __shfl_xor(pg3, m);
        }
        if (lrow == 0) {
            const int base = wv * 16 + lkg * 4;
            pV[base + 0] = pv0; pV[base + 1] = pv1;
            pV[base + 2] = pv2; pV[base + 3] = pv3;
            pG[base + 0] = pg0; pG[base + 1] = pg1;
            pG[base + 2] = pg2; pG[base + 3] = pg3;
        }
    }

    // ---- NW1 GEMM (K=128) -> silu -> tileM ----
    f32x4 accH;
    { const float b = sNB1[ch]; f32x4 v = {b, b, b, b}; accH = v; }
    {
        U4H8 w0, w1, w2, w3;
        w0.u = ((const uint4*)sNW1S)[ch * 16 + ((0 + lkg) ^ ch15)];
        w1.u = ((const uint4*)sNW1S)[ch * 16 + ((4 + lkg) ^ ch15)];
        w2.u = ((const uint4*)sNW1S)[ch * 16 + ((8 + lkg) ^ ch15)];
        w3.u = ((const uint4*)sNW1S)[ch * 16 + ((12 + lkg) ^ ch15)];
        accH = __builtin_amdgcn_mfma_f32_16x16x32_f16(aA0.h, w0.h, accH, 0, 0, 0);
        accH = __builtin_amdgcn_mfma_f32_16x16x32_f16(aA1.h, w1.h, accH, 0, 0, 0);
        accH = __builtin_amdgcn_mfma_f32_16x16x32_f16(aA2.h, w2.h, accH, 0, 0, 0);
        accH = __builtin_amdgcn_mfma_f32_16x16x32_f16(aA3.h, w3.h, accH, 0, 0, 0);
    }
    {
        ushort_t* tm16 = (ushort_t*)tileM;
        const int wi = ch >> 1;
        const int wg = wi >> 2, wj = wi & 3, hl = ch & 1;
        #pragma unroll
        for (int r2 = 0; r2 < 4; r2++) {
            const int node = lkg * 4 + r2;
            tm16[(node * 32 + ((wg ^ (node & 7)) << 2) + wj) * 2 + hl] =
                f2hbits(silu(accH[r2]));
        }
    }
    __syncthreads();

    // ---- combine vw/gw; coord update; zero magg/csum ----
    if (q == 0) {
        const float vw = gVB2[0] + pV[ni] + pV[16 + ni] + pV[32 + ni] + pV[48 + ni];
        const float gw = gGB2[0] + pG[ni] + pG[16 + ni] + pG[32 + ni] + pG[48 + ni];
        const float cn = fmaxf((float)(off[n + 1] - off[n]), 1.0f);
        #pragma unroll
        for (int d = 0; d < 3; d++)
            coord[3 * n + d] += csum[3 * n + d] / cn
                              + vw * vsrc[3 * n + d]
                              + gw * field[3 * n + d];
        csum[3 * n] = 0.f; csum[3 * n + 1] = 0.f; csum[3 * n + 2] = 0.f;
    }
    {
        float4 z; z.x = z.y = z.z = z.w = 0.f;
        ((float4*)(magg + (size_t)n * 64))[q] = z;
    }

    // ---- NW2 GEMM (K=64 from tileM) -> hh ----
    f32x4 accO;
    { const float b = sNB2[ch]; f32x4 v = {b, b, b, b}; accO = v; }
    {
        U4H8 m0, m1, w0, w1;
        m0.u = ((const uint4*)tileM)[lrow * 8 + (lkg ^ (lrow & 7))];
        m1.u = ((const uint4*)tileM)[lrow * 8 + ((4 + lkg) ^ (lrow & 7))];
        w0.u = ((const uint4*)sNW2S)[ch * 8 + (lkg ^ ch7)];
        w1.u = ((const uint4*)sNW2S)[ch * 8 + ((4 + lkg) ^ ch7)];
        accO = __builtin_amdgcn_mfma_f32_16x16x32_f16(m0.h, w0.h, accO, 0, 0, 0);
        accO = __builtin_amdgcn_mfma_f32_16x16x32_f16(m1.h, w1.h, accO, 0, 0, 0);
    }
    #pragma unroll
    for (int r2 = 0; r2 < 4; r2++)
        hh[(size_t)(nb + lkg * 4 + r2) * 64 + ch] = accO[r2];

    // ---- fused pre emission for next layer ----
    if (emit_pre) {
        // pack new hh (f16) into tileA pairs 0..31 (C/D scatter)
        {
            ushort_t* ta16 = (ushort_t*)tileA;
            const int wi = ch >> 1;
            const int wg = wi >> 2, wj = wi & 3, hl = ch & 1;
            #pragma unroll
            for (int r2 = 0; r2 < 4; r2++) {
                const int node = lkg * 4 + r2;
                ta16[(node * 64 + ((wg ^ (node & 15)) << 2) + wj) * 2 + hl] =
                    f2hbits(accO[r2]);
            }
        }
        __syncthreads();
        U4H8 h0, h1, wr0, wr1, wc0, wc1;
        h0.u = ((const uint4*)tileA)[lrow * 16 + ((0 + lkg) ^ lrow)];
        h1.u = ((const uint4*)tileA)[lrow * 16 + ((4 + lkg) ^ lrow)];
        wr0.u = ((const uint4*)sW1nS)[ch * 8 + (lkg ^ ch7)];
        wr1.u = ((const uint4*)sW1nS)[ch * 8 + ((4 + lkg) ^ ch7)];
        wc0.u = ((const uint4*)sW1nS)[(64 + ch) * 8 + (lkg ^ ch7)];
        wc1.u = ((const uint4*)sW1nS)[(64 + ch) * 8 + ((4 + lkg) ^ ch7)];
        f32x4 accR, accC;
        { const float b = sB1n[ch]; f32x4 v = {b, b, b, b}; accR = v; }
        { f32x4 v = {0.f, 0.f, 0.f, 0.f}; accC = v; }
        accR = __builtin_amdgcn_mfma_f32_16x16x32_f16(h0.h, wr0.h, accR, 0, 0, 0);
        accR = __builtin_amdgcn_mfma_f32_16x16x32_f16(h1.h, wr1.h, accR, 0, 0, 0);
        accC = __builtin_amdgcn_mfma_f32_16x16x32_f16(h0.h, wc0.h, accC, 0, 0, 0);
        accC = __builtin_amdgcn_mfma_f32_16x16x32_f16(h1.h, wc1.h, accC, 0, 0, 0);
        ushort_t* pRu = (ushort_t*)preR;
        ushort_t* pCu = (ushort_t*)preC;
        #pragma unroll
        for (int r2 = 0; r2 < 4; r2++) {
            const size_t g = (size_t)(nb + lkg * 4 + r2) * 64 + ch;
            pRu[g] = f2hbits(accR[r2]);
            pCu[g] = f2hbits(accC[r2]);
        }
    }
}

// ---- host launch -------------------------------------------------------------
extern "C" void kernel_launch(void* const* d_in, const int* in_sizes, int n_in,
                              void* d_out, int out_size, void* d_ws, size_t ws_size,
                              hipStream_t stream) {
    float* wsf = (float*)d_ws;
    int*   wsi = (int*)(wsf + 1340000);
    uint_t* preR  = (uint_t*)(wsi + IOFF_PRER);
    uint_t* preC  = (uint_t*)(wsi + IOFF_PREC);
    uint_t* wconv = (uint_t*)(wsi + IOFF_WCONV);
    float* coord = (float*)d_out;
    const int* edges = (const int*)d_in[4];
    const int* rows = edges;
    const int* cols = edges + NE;

    hipMemsetAsync(wsi + IOFF_CNTI, 0, NN * sizeof(int), stream);
    wconv_kernel<<<NL, 256, 0, stream>>>(
        (const float*)d_in[15], (const float*)d_in[17], (const float*)d_in[23],
        (const float*)d_in[26], (const float*)d_in[30], (const float*)d_in[19],
        (const float*)d_in[21],
        wconv);
    counti_kernel<<<(NE + 255) / 256, 256, 0, stream>>>(rows, wsi + IOFF_CNTI);
    scan_kernel<<<1, 1024, 0, stream>>>(wsi + IOFF_CNTI, wsi + IOFF_OFF, wsi + IOFF_CURSOR);
    scatter_kernel<<<(NE + 255) / 256, 256, 0, stream>>>(rows, wsi + IOFF_CURSOR,
                                                         wsi + IOFF_PERM);

    node_init<<<(NN + 255) / 256, 256, 0, stream>>>(
        (const float*)d_in[0], (const float*)d_in[1], (const float*)d_in[2],
        (const int*)d_in[5], (const float*)d_in[8],
        (const float*)d_in[9],  (const float*)d_in[10],
        (const float*)d_in[11], (const float*)d_in[12],
        (const float*)d_in[13], (const float*)d_in[14],
        (const float*)d_in[6],  (const float*)d_in[7],
        coord, wsf + OFF_FIELD, wsf + OFF_HH);

    hipMemsetAsync(wsf + OFF_CSUM, 0, (30000 + 640000) * sizeof(float), stream);

    pre_kernel<<<NNODEBLK, 256, 0, stream>>>(
        wsf + OFF_HH,
        wconv + 0 * WC_SIZE + WC_EW1, (const float*)d_in[16],
        preR, preC);

    for (int l = 0; l < NL; l++) {
        const int ln = (l + 1 < NL) ? (l + 1) : 0;
        edge_kernel<<<NEBLK, 256, 0, stream>>>(
            rows, cols, wsi + IOFF_PERM,
            coord, (const float*)d_in[3],
            ((const float*)d_in[15]) + l * 8384,
            wconv + l * WC_SIZE,
            ((const float*)d_in[18]) + l * 64,
            ((const float*)d_in[24]) + l * 64,
            ((const float*)d_in[25]) + l * 64,
            preR, preC,
            wsf + OFF_CSUM, wsf + OFF_MAGG);
        node_kernel<<<NODEBLK2, 256, 0, stream>>>(
            wconv + l * WC_SIZE, wconv + ln * WC_SIZE,
            ((const float*)d_in[27]) + l * 64,
            ((const float*)d_in[28]) + l * 64,   ((const float*)d_in[29]) + l,
            ((const float*)d_in[31]) + l * 64,
            ((const float*)d_in[32]) + l * 64,   ((const float*)d_in[33]) + l,
            ((const float*)d_in[20]) + l * 64,   ((const float*)d_in[22]) + l * 64,
            ((const float*)d_in[16]) + ln * 64,
            wsf + OFF_CSUM, wsi + IOFF_OFF, (const float*)d_in[2],
            wsf + OFF_FIELD, wsf + OFF_MAGG, coord, wsf + OFF_HH,
            preR, preC, (l + 1 < NL) ? 1 : 0);
    }
}